// Round 1
// baseline (12038.261 us; speedup 1.0000x reference)
//
#include <hip/hip_runtime.h>
#include <hip/hip_bf16.h>

// Problem constants
// IN=128, H=512, N=2048, W=64, OUT=128, R=4, T=128, B=64
// ctrl_in = 384, combined gate K = 896, gate rows = 2048, out+key rows = 448
#define EPSF 1e-8f

typedef __attribute__((ext_vector_type(8))) __bf16 bf8;
typedef __attribute__((ext_vector_type(4))) float f4;

__device__ __forceinline__ short f2bf(float f) {
  union { __hip_bfloat16 b; short s; } u;
  u.b = __float2bfloat16(f);
  return u.s;
}
__device__ __forceinline__ float sigf(float x) { return 1.f / (1.f + __expf(-x)); }
__device__ __forceinline__ float red16(float v) {
  v += __shfl_xor(v, 1); v += __shfl_xor(v, 2);
  v += __shfl_xor(v, 4); v += __shfl_xor(v, 8);
  return v;
}

// ---------------- weight conversion (once per call) ----------------
__global__ __launch_bounds__(256) void k_wcvt(
    const float* __restrict__ Wih, const float* __restrict__ Whh,
    const float* __restrict__ Wout, const float* __restrict__ Wkey,
    short* __restrict__ Wc, short* __restrict__ Wkb) {
  int gid = blockIdx.x * 256 + threadIdx.x;
  int gs = gridDim.x * 256;
  for (int i = gid; i < 2048 * 896; i += gs) {
    int row = i / 896, k = i - row * 896;
    float v = (k < 384) ? Wih[row * 384 + k] : Whh[row * 512 + (k - 384)];
    Wc[i] = f2bf(v);
  }
  for (int i = gid; i < 448 * 512; i += gs) {
    int row = i >> 9, k = i & 511;
    float v = (row < 128) ? Wout[row * 512 + k] : Wkey[(row - 128) * 512 + k];
    Wkb[i] = f2bf(v);
  }
}

// ---------------- state init (every call; ws is poisoned) ----------------
__global__ __launch_bounds__(256) void k_init(
    float* __restrict__ M, float* __restrict__ rwA, float* __restrict__ usage,
    float* __restrict__ c, short* __restrict__ hA, float* __restrict__ read_vec,
    float* __restrict__ sumA) {
  size_t gid = (size_t)blockIdx.x * 256 + threadIdx.x;
  size_t gs = (size_t)gridDim.x * 256;
  for (size_t i = gid; i < 8388608u; i += gs) M[i] = 1e-6f;
  for (size_t i = gid; i < 524288u; i += gs) rwA[i] = 0.f;
  for (size_t i = gid; i < 131072u; i += gs) usage[i] = 0.f;
  for (size_t i = gid; i < 32768u; i += gs) { c[i] = 0.f; hA[i] = 0; }
  for (size_t i = gid; i < 16384u; i += gs) read_vec[i] = 0.f;
  if (gid < 256) sumA[gid] = 1.f;  // prev softmax denom = 1 so prev read_w == 0
}

// ---------------- K1: gates GEMM (bf16 MFMA) + LSTM cell ----------------
// grid 64 blocks: block handles j-chunk of 8 -> rows {g*512 + j0 + jj}
__global__ __launch_bounds__(256) void k_gates(
    const float* __restrict__ x_seq, const short* __restrict__ Wc,
    const float* __restrict__ bih, const float* __restrict__ bhh,
    const float* __restrict__ read_vec, const short* __restrict__ h_prev,
    float* __restrict__ c, short* __restrict__ h_new, int t) {
  __shared__ __align__(16) short Xs[64 * 72];  // 64 rows x 64 k bf16, stride 72
  __shared__ __align__(16) short Ws[32 * 72];
  __shared__ float gbuf[64 * 33];
  const int tid = threadIdx.x;
  const int lane = tid & 63;
  const int wv = tid >> 6;
  const int j0 = blockIdx.x * 8;
  const int m = lane & 15;
  const int quad = lane >> 4;

  f4 acc0 = {0.f, 0.f, 0.f, 0.f}, acc1 = {0.f, 0.f, 0.f, 0.f};

  for (int kc = 0; kc < 14; ++kc) {
    const int kbase = kc * 64;
    __syncthreads();
    if (kbase < 128) {
      for (int p = 0; p < 8; ++p) {
        int i = p * 256 + tid;
        int row = i >> 5, kp = i & 31;
        float2 v = *(const float2*)&x_seq[((size_t)t * 64 + row) * 128 + kbase + kp * 2];
        short2 o; o.x = f2bf(v.x); o.y = f2bf(v.y);
        *(short2*)&Xs[row * 72 + kp * 2] = o;
      }
    } else if (kbase < 384) {
      for (int p = 0; p < 8; ++p) {
        int i = p * 256 + tid;
        int row = i >> 5, kp = i & 31;
        float2 v = *(const float2*)&read_vec[row * 256 + (kbase - 128) + kp * 2];
        short2 o; o.x = f2bf(v.x); o.y = f2bf(v.y);
        *(short2*)&Xs[row * 72 + kp * 2] = o;
      }
    } else {
      for (int p = 0; p < 8; ++p) {
        int i = p * 256 + tid;
        int row = i >> 5, kp = i & 31;
        *(short2*)&Xs[row * 72 + kp * 2] =
            *(const short2*)&h_prev[row * 512 + (kbase - 384) + kp * 2];
      }
    }
    for (int p = 0; p < 4; ++p) {
      int i = p * 256 + tid;
      int row = i >> 5, kp = i & 31;
      int g = row >> 3, jj = row & 7;
      int grow = g * 512 + j0 + jj;
      *(short2*)&Ws[row * 72 + kp * 2] =
          *(const short2*)&Wc[(size_t)grow * 896 + kbase + kp * 2];
    }
    __syncthreads();
#pragma unroll
    for (int ki = 0; ki < 2; ++ki) {
      int ko = ki * 32 + quad * 8;
      bf8 a = *(const bf8*)&Xs[(16 * wv + m) * 72 + ko];
      bf8 b0 = *(const bf8*)&Ws[m * 72 + ko];
      bf8 b1 = *(const bf8*)&Ws[(16 + m) * 72 + ko];
      acc0 = __builtin_amdgcn_mfma_f32_16x16x32_bf16(a, b0, acc0, 0, 0, 0);
      acc1 = __builtin_amdgcn_mfma_f32_16x16x32_bf16(a, b1, acc1, 0, 0, 0);
    }
  }
  // D[m=quad*4+reg][n=lane&15]; batch = 16*wv + quad*4 + reg; lr = f*16 + n
#pragma unroll
  for (int reg = 0; reg < 4; ++reg) {
    int b = 16 * wv + quad * 4 + reg;
    gbuf[b * 33 + m] = acc0[reg];
    gbuf[b * 33 + 16 + m] = acc1[reg];
  }
  __syncthreads();
  // cell update: lr = g*8 + jj
  for (int s2 = 0; s2 < 2; ++s2) {
    int p = s2 * 256 + tid;
    int b = p & 63, jj = p >> 6;
    int j = j0 + jj;
    float gi = gbuf[b * 33 + jj] + bih[j] + bhh[j];
    float gf = gbuf[b * 33 + 8 + jj] + bih[512 + j] + bhh[512 + j];
    float gg = gbuf[b * 33 + 16 + jj] + bih[1024 + j] + bhh[1024 + j];
    float go = gbuf[b * 33 + 24 + jj] + bih[1536 + j] + bhh[1536 + j];
    float co = c[b * 512 + j];
    float cn = sigf(gf) * co + sigf(gi) * tanhf(gg);
    float hn = sigf(go) * tanhf(cn);
    c[b * 512 + j] = cn;
    h_new[b * 512 + j] = f2bf(hn);
  }
}

// ---------------- K3: out + keys GEMM (bf16 MFMA) ----------------
// grid 14 blocks of 32 rows; rows 0..127 -> out, 128..447 -> keys
__global__ __launch_bounds__(256) void k_outkeys(
    const short* __restrict__ h, const short* __restrict__ Wkb,
    const float* __restrict__ bout, const float* __restrict__ bkey,
    float* __restrict__ out, float* __restrict__ keys,
    float* __restrict__ sum_new, float* __restrict__ read_vec, int t) {
  __shared__ __align__(16) short Xs[64 * 72];
  __shared__ __align__(16) short Ws[32 * 72];
  const int tid = threadIdx.x;
  const int lane = tid & 63;
  const int wv = tid >> 6;
  const int m = lane & 15;
  const int quad = lane >> 4;
  const int row0 = blockIdx.x * 32;
  f4 accs[2];
  accs[0] = (f4){0.f, 0.f, 0.f, 0.f};
  accs[1] = (f4){0.f, 0.f, 0.f, 0.f};
  for (int kc = 0; kc < 8; ++kc) {
    int kbase = kc * 64;
    __syncthreads();
    for (int p = 0; p < 8; ++p) {
      int i = p * 256 + tid;
      int row = i >> 5, kp = i & 31;
      *(short2*)&Xs[row * 72 + kp * 2] =
          *(const short2*)&h[row * 512 + kbase + kp * 2];
    }
    for (int p = 0; p < 4; ++p) {
      int i = p * 256 + tid;
      int row = i >> 5, kp = i & 31;
      *(short2*)&Ws[row * 72 + kp * 2] =
          *(const short2*)&Wkb[(size_t)(row0 + row) * 512 + kbase + kp * 2];
    }
    __syncthreads();
#pragma unroll
    for (int ki = 0; ki < 2; ++ki) {
      int ko = ki * 32 + quad * 8;
      bf8 a = *(const bf8*)&Xs[(16 * wv + m) * 72 + ko];
      bf8 b0 = *(const bf8*)&Ws[m * 72 + ko];
      bf8 b1 = *(const bf8*)&Ws[(16 + m) * 72 + ko];
      accs[0] = __builtin_amdgcn_mfma_f32_16x16x32_bf16(a, b0, accs[0], 0, 0, 0);
      accs[1] = __builtin_amdgcn_mfma_f32_16x16x32_bf16(a, b1, accs[1], 0, 0, 0);
    }
  }
#pragma unroll
  for (int f = 0; f < 2; ++f) {
#pragma unroll
    for (int reg = 0; reg < 4; ++reg) {
      int b = 16 * wv + quad * 4 + reg;
      int grow = row0 + f * 16 + m;
      float val = accs[f][reg];
      if (grow < 128)
        out[((size_t)t * 64 + b) * 128 + grow] = val + bout[grow];
      else
        keys[b * 320 + (grow - 128)] = val + bkey[grow - 128];
    }
  }
  if (blockIdx.x == 0) {
    sum_new[tid] = 0.f;
    for (int i = tid; i < 16384; i += 256) read_vec[i] = 0.f;
  }
}

// ---------------- K5: cosine sim + exp + denom sums + argmin(usage) ----------
// grid 512 blocks: blockIdx = b*8 + chunk(256 n's)
__global__ __launch_bounds__(256) void k_sim(
    const float* __restrict__ M, const float* __restrict__ keys,
    float* __restrict__ rw_new, float* __restrict__ sum_new,
    const float* __restrict__ usage, int* __restrict__ lu_idx) {
  const int tid = threadIdx.x;
  const int lane = tid & 63;
  const int wv = tid >> 6;
  const int s = lane & 15;
  const int q = lane >> 4;
  const int b = blockIdx.x >> 3;
  const int ch = blockIdx.x & 7;
  const float4* M4 = (const float4*)M;
  const float4* K4 = (const float4*)keys;
  float4 kn[4];
#pragma unroll
  for (int r = 0; r < 4; ++r) {
    float4 k4 = K4[b * 80 + r * 16 + s];
    float ss = k4.x * k4.x + k4.y * k4.y + k4.z * k4.z + k4.w * k4.w;
    ss = red16(ss);
    float iv = 1.f / (sqrtf(ss) + EPSF);
    kn[r].x = k4.x * iv; kn[r].y = k4.y * iv; kn[r].z = k4.z * iv; kn[r].w = k4.w * iv;
  }
  float es0 = 0.f, es1 = 0.f, es2 = 0.f, es3 = 0.f;
  for (int i = 0; i < 16; ++i) {
    int n = ch * 256 + wv * 64 + i * 4 + q;
    float4 m4 = M4[((size_t)b * 2048 + n) * 16 + s];
    float ssm = m4.x * m4.x + m4.y * m4.y + m4.z * m4.z + m4.w * m4.w;
    float d0 = m4.x * kn[0].x + m4.y * kn[0].y + m4.z * kn[0].z + m4.w * kn[0].w;
    float d1 = m4.x * kn[1].x + m4.y * kn[1].y + m4.z * kn[1].z + m4.w * kn[1].w;
    float d2 = m4.x * kn[2].x + m4.y * kn[2].y + m4.z * kn[2].z + m4.w * kn[2].w;
    float d3 = m4.x * kn[3].x + m4.y * kn[3].y + m4.z * kn[3].z + m4.w * kn[3].w;
    ssm = red16(ssm);
    d0 = red16(d0); d1 = red16(d1); d2 = red16(d2); d3 = red16(d3);
    float iv = 1.f / (sqrtf(ssm) + EPSF);
    if (s == 0) {
      // exp without max-subtraction: cosine in [-1,1], perfectly safe
      float e0 = __expf(d0 * iv), e1 = __expf(d1 * iv);
      float e2 = __expf(d2 * iv), e3 = __expf(d3 * iv);
      rw_new[(b * 4 + 0) * 2048 + n] = e0;
      rw_new[(b * 4 + 1) * 2048 + n] = e1;
      rw_new[(b * 4 + 2) * 2048 + n] = e2;
      rw_new[(b * 4 + 3) * 2048 + n] = e3;
      es0 += e0; es1 += e1; es2 += e2; es3 += e3;
    }
  }
  es0 += __shfl_xor(es0, 16); es0 += __shfl_xor(es0, 32);
  es1 += __shfl_xor(es1, 16); es1 += __shfl_xor(es1, 32);
  es2 += __shfl_xor(es2, 16); es2 += __shfl_xor(es2, 32);
  es3 += __shfl_xor(es3, 16); es3 += __shfl_xor(es3, 32);
  if (lane == 0) {
    atomicAdd(&sum_new[b * 4 + 0], es0);
    atomicAdd(&sum_new[b * 4 + 1], es1);
    atomicAdd(&sum_new[b * 4 + 2], es2);
    atomicAdd(&sum_new[b * 4 + 3], es3);
  }
  if (ch == 0) {
    __shared__ float sv[256];
    __shared__ int si[256];
    float vm = INFINITY;
    int im = 0x7fffffff;
    for (int i2 = 0; i2 < 8; ++i2) {
      int n = i2 * 256 + tid;
      float v = usage[b * 2048 + n];
      if (v < vm || (v == vm && n < im)) { vm = v; im = n; }
    }
    sv[tid] = vm; si[tid] = im;
    __syncthreads();
    for (int off = 128; off > 0; off >>= 1) {
      if (tid < off) {
        float v2 = sv[tid + off]; int j2 = si[tid + off];
        if (v2 < sv[tid] || (v2 == sv[tid] && j2 < si[tid])) { sv[tid] = v2; si[tid] = j2; }
      }
      __syncthreads();
    }
    if (tid == 0) lu_idx[b] = si[0];
  }
}

// ---------------- K7: read_vec + memory write + usage update (fused) --------
// grid 256 blocks: blockIdx = b*4 + chunk(512 n's)
__global__ __launch_bounds__(256) void k_update(
    float* __restrict__ M, const float* __restrict__ keys,
    const float* __restrict__ rw_new, const float* __restrict__ sum_new,
    const float* __restrict__ rw_prev, const float* __restrict__ sum_prev,
    float* __restrict__ usage, const int* __restrict__ lu_idx,
    float* __restrict__ read_vec, const float* __restrict__ alpha_p,
    const float* __restrict__ gamma_p) {
  const int tid = threadIdx.x;
  const int lane = tid & 63;
  const int wv = tid >> 6;
  const int s = lane & 15;
  const int q = lane >> 4;
  const int b = blockIdx.x >> 2;
  const int ch = blockIdx.x & 3;
  float4* M4 = (float4*)M;
  const float4* K4 = (const float4*)keys;
  const float sa = sigf(alpha_p[0]);
  const float gam = gamma_p[0];
  const int lu = lu_idx[b];
  const float4 wk = K4[b * 80 + 64 + s];
  const float iN0 = 1.f / sum_new[b * 4 + 0];
  const float iN1 = 1.f / sum_new[b * 4 + 1];
  const float iN2 = 1.f / sum_new[b * 4 + 2];
  const float iN3 = 1.f / sum_new[b * 4 + 3];
  const float iP0 = 1.f / sum_prev[b * 4 + 0];
  const float iP1 = 1.f / sum_prev[b * 4 + 1];
  const float iP2 = 1.f / sum_prev[b * 4 + 2];
  const float iP3 = 1.f / sum_prev[b * 4 + 3];
  const float* rn0 = rw_new + (b * 4 + 0) * 2048;
  const float* rn1 = rw_new + (b * 4 + 1) * 2048;
  const float* rn2 = rw_new + (b * 4 + 2) * 2048;
  const float* rn3 = rw_new + (b * 4 + 3) * 2048;
  const float* rp0 = rw_prev + (b * 4 + 0) * 2048;
  const float* rp1 = rw_prev + (b * 4 + 1) * 2048;
  const float* rp2 = rw_prev + (b * 4 + 2) * 2048;
  const float* rp3 = rw_prev + (b * 4 + 3) * 2048;
  float4 rv0 = {0, 0, 0, 0}, rv1 = {0, 0, 0, 0}, rv2 = {0, 0, 0, 0}, rv3 = {0, 0, 0, 0};
  for (int i = 0; i < 32; ++i) {
    const int n = ch * 512 + wv * 128 + i * 4 + q;
    const size_t mi = ((size_t)b * 2048 + n) * 16 + s;
    float4 m4 = M4[mi];
    float e0 = rn0[n] * iN0, e1 = rn1[n] * iN1, e2 = rn2[n] * iN2, e3 = rn3[n] * iN3;
    rv0.x += e0 * m4.x; rv0.y += e0 * m4.y; rv0.z += e0 * m4.z; rv0.w += e0 * m4.w;
    rv1.x += e1 * m4.x; rv1.y += e1 * m4.y; rv1.z += e1 * m4.z; rv1.w += e1 * m4.w;
    rv2.x += e2 * m4.x; rv2.y += e2 * m4.y; rv2.z += e2 * m4.z; rv2.w += e2 * m4.w;
    rv3.x += e3 * m4.x; rv3.y += e3 * m4.y; rv3.z += e3 * m4.z; rv3.w += e3 * m4.w;
    float wps = rp0[n] * iP0 + rp1[n] * iP1 + rp2[n] * iP2 + rp3[n] * iP3;
    float onehot = (n == lu) ? 1.f : 0.f;
    float ww = sa * wps + (1.f - sa) * onehot;
    float keep = 1.f - onehot;
    float4 mn;
    mn.x = m4.x * keep + ww * wk.x;
    mn.y = m4.y * keep + ww * wk.y;
    mn.z = m4.z * keep + ww * wk.z;
    mn.w = m4.w * keep + ww * wk.w;
    M4[mi] = mn;
    if (s == 0) {
      usage[b * 2048 + n] = gam * usage[b * 2048 + n] + (e0 + e1 + e2 + e3) + ww;
    }
  }
#define REDQ(v) { v += __shfl_xor(v, 16); v += __shfl_xor(v, 32); }
  REDQ(rv0.x) REDQ(rv0.y) REDQ(rv0.z) REDQ(rv0.w)
  REDQ(rv1.x) REDQ(rv1.y) REDQ(rv1.z) REDQ(rv1.w)
  REDQ(rv2.x) REDQ(rv2.y) REDQ(rv2.z) REDQ(rv2.w)
  REDQ(rv3.x) REDQ(rv3.y) REDQ(rv3.z) REDQ(rv3.w)
#undef REDQ
  if (q == 0) {
    float* dst = read_vec + b * 256;
    atomicAdd(dst + 0 * 64 + s * 4 + 0, rv0.x);
    atomicAdd(dst + 0 * 64 + s * 4 + 1, rv0.y);
    atomicAdd(dst + 0 * 64 + s * 4 + 2, rv0.z);
    atomicAdd(dst + 0 * 64 + s * 4 + 3, rv0.w);
    atomicAdd(dst + 1 * 64 + s * 4 + 0, rv1.x);
    atomicAdd(dst + 1 * 64 + s * 4 + 1, rv1.y);
    atomicAdd(dst + 1 * 64 + s * 4 + 2, rv1.z);
    atomicAdd(dst + 1 * 64 + s * 4 + 3, rv1.w);
    atomicAdd(dst + 2 * 64 + s * 4 + 0, rv2.x);
    atomicAdd(dst + 2 * 64 + s * 4 + 1, rv2.y);
    atomicAdd(dst + 2 * 64 + s * 4 + 2, rv2.z);
    atomicAdd(dst + 2 * 64 + s * 4 + 3, rv2.w);
    atomicAdd(dst + 3 * 64 + s * 4 + 0, rv3.x);
    atomicAdd(dst + 3 * 64 + s * 4 + 1, rv3.y);
    atomicAdd(dst + 3 * 64 + s * 4 + 2, rv3.z);
    atomicAdd(dst + 3 * 64 + s * 4 + 3, rv3.w);
  }
}

extern "C" void kernel_launch(void* const* d_in, const int* in_sizes, int n_in,
                              void* d_out, int out_size, void* d_ws, size_t ws_size,
                              hipStream_t stream) {
  const float* x_seq = (const float*)d_in[0];
  const float* Wih = (const float*)d_in[1];
  const float* Whh = (const float*)d_in[2];
  const float* bih = (const float*)d_in[3];
  const float* bhh = (const float*)d_in[4];
  const float* Wout = (const float*)d_in[5];
  const float* bout = (const float*)d_in[6];
  const float* Wkey = (const float*)d_in[7];
  const float* bkey = (const float*)d_in[8];
  const float* alpha = (const float*)d_in[9];
  const float* gamma = (const float*)d_in[10];
  float* out = (float*)d_out;

  char* w = (char*)d_ws;
  float* M = (float*)(w + 0);                 // 33554432 B
  float* rwA = (float*)(w + 33554432);        // 2097152 B
  float* rwB = (float*)(w + 35651584);        // 2097152 B
  float* usage = (float*)(w + 37748736);      // 524288 B
  float* c = (float*)(w + 38273024);          // 131072 B
  short* hA = (short*)(w + 38404096);         // 65536 B
  short* hB = (short*)(w + 38469632);         // 65536 B
  float* read_vec = (float*)(w + 38535168);   // 65536 B
  float* keys = (float*)(w + 38600704);       // 81920 B
  float* sumA = (float*)(w + 38682624);       // 1024 B
  float* sumB = (float*)(w + 38683648);       // 1024 B
  int* lu_idx = (int*)(w + 38684672);         // 256 B
  short* Wc = (short*)(w + 38684928);         // 3670016 B
  short* Wkb = (short*)(w + 42354944);        // 458752 B  -> total ~42.8 MB

  k_wcvt<<<1024, 256, 0, stream>>>(Wih, Whh, Wout, Wkey, Wc, Wkb);
  k_init<<<2048, 256, 0, stream>>>(M, rwA, usage, c, hA, read_vec, sumA);

  float* rw_prev = rwA; float* rw_new = rwB;
  float* sum_prev = sumA; float* sum_new = sumB;
  short* h_prev = hA; short* h_new = hB;

  for (int t = 0; t < 128; ++t) {
    k_gates<<<64, 256, 0, stream>>>(x_seq, Wc, bih, bhh, read_vec, h_prev, c, h_new, t);
    k_outkeys<<<14, 256, 0, stream>>>(h_new, Wkb, bout, bkey, out, keys, sum_new, read_vec, t);
    k_sim<<<512, 256, 0, stream>>>(M, keys, rw_new, sum_new, usage, lu_idx);
    k_update<<<256, 256, 0, stream>>>(M, keys, rw_new, sum_new, rw_prev, sum_prev,
                                      usage, lu_idx, read_vec, alpha, gamma);
    float* tf = rw_prev; rw_prev = rw_new; rw_new = tf;
    tf = sum_prev; sum_prev = sum_new; sum_new = tf;
    short* ts = h_prev; h_prev = h_new; h_new = ts;
  }
}